// Round 7
// baseline (174.785 us; speedup 1.0000x reference)
//
#include <hip/hip_runtime.h>
#include <hip/hip_bf16.h>

#define B_N 8192
#define D_K 256
#define MARGIN 0.3f

typedef float f32x4 __attribute__((ext_vector_type(4)));
typedef short s16x8 __attribute__((ext_vector_type(8)));

// Order-preserving float->uint for atomicMax/atomicMin on floats.
__device__ __forceinline__ unsigned fkey(float f) {
    unsigned u = __float_as_uint(f);
    return (u & 0x80000000u) ? ~u : (u | 0x80000000u);
}
__device__ __forceinline__ float kval(unsigned k) {
    return (k & 0x80000000u) ? __uint_as_float(k ^ 0x80000000u)
                             : __uint_as_float(~k);
}

// async 16B global -> LDS (LDS dest = wave-uniform base + lane*16)
__device__ __forceinline__ void load_lds16(const unsigned short* g,
                                           unsigned short* l) {
    __builtin_amdgcn_global_load_lds(
        (const __attribute__((address_space(1))) unsigned int*)g,
        (__attribute__((address_space(3))) unsigned int*)l, 16, 0, 0);
}

// ---- kernel 1: bf16 round + norms OF ROUNDED VALUES + init ----------------
// Xp layout: [row][k] bf16, row stride 256 shorts (512 B).
// sq[row] = sum(hi^2) in fp32 -> dist is exactly ||xh_i - xh_j||^2 (stable).
__global__ __launch_bounds__(256) void prep_kernel(const float* __restrict__ X,
        float* __restrict__ sq, unsigned* __restrict__ apk,
        unsigned* __restrict__ ank, unsigned short* __restrict__ Xp,
        float* __restrict__ acc2) {
    int row  = (blockIdx.x << 2) + (threadIdx.x >> 6);
    int lane = threadIdx.x & 63;
    const float4 v = reinterpret_cast<const float4*>(X + (size_t)row * D_K)[lane];

    float xs[4] = {v.x, v.y, v.z, v.w};
    ushort4 hv;
    unsigned short* hp = &hv.x;
    float s = 0.f;
    #pragma unroll
    for (int i = 0; i < 4; ++i) {
        __hip_bfloat16 h = __float2bfloat16(xs[i]);
        hp[i] = *reinterpret_cast<unsigned short*>(&h);
        float hf = __bfloat162float(h);
        s = fmaf(hf, hf, s);
    }
    *reinterpret_cast<ushort4*>(Xp + (size_t)row * D_K + lane * 4) = hv;

    #pragma unroll
    for (int o = 32; o > 0; o >>= 1) s += __shfl_down(s, o, 64);
    if (lane == 0) {
        sq[row]  = s;
        apk[row] = 0u;           // <= fkey(-inf)
        ank[row] = 0xFFFFFFFFu;  // >= fkey(+inf)
    }
    if (blockIdx.x == 0 && threadIdx.x == 0) {
        acc2[0] = 0.f; acc2[1] = 0.f;
        reinterpret_cast<unsigned*>(acc2)[2] = 0u;   // ticket counter
    }
}

// ---- kernel 2: LDS-staged single-bf16 MFMA dist, 4 tiles/block ------------
#define BM 128
#define BN 128
#define NTILE 4
// LDS tile per operand: 128 rows x 64 shorts (one 64-k window; 8x16B units,
// unit u of row r stored at slot u^(r&7) -> 2 lanes/bank on ds_read_b128)

__global__ __launch_bounds__(256) void dist_kernel(
        const unsigned short* __restrict__ Xp,
        const int* __restrict__ tgt, const float* __restrict__ sq,
        unsigned* __restrict__ apk, unsigned* __restrict__ ank) {
    __shared__ unsigned short Atile[128 * 64];   // 16 KB
    __shared__ unsigned short Btile[128 * 64];   // 16 KB

    const int t    = threadIdx.x;
    const int lane = t & 63;
    const int wave = t >> 6;
    const int wrow = (wave >> 1) * 64;
    const int wcol = (wave & 1) * 64;
    const int fr   = lane & 15;
    const int quad = lane >> 4;
    const float INF = __int_as_float(0x7f800000);

    // staging geometry (tile-independent): thread's 4 units per operand
    int   sg_r[4], sg_u[4];
    unsigned short* al[4];
    unsigned short* bl[4];
    #pragma unroll
    for (int j = 0; j < 4; ++j) {
        int g = wave * 64 + j * 256 + lane;   // 0..1023
        int r = g >> 3, s0 = g & 7;
        sg_r[j] = r;
        sg_u[j] = s0 ^ (r & 7);
        al[j] = Atile + g * 8;                // wave base + lane*16B
        bl[j] = Btile + g * 8;
    }

    #pragma unroll 1
    for (int tile = 0; tile < NTILE; ++tile) {
        int tt = blockIdx.x * NTILE + tile;   // 0..2079
        // triangular decode: tt -> (bx, by), by <= bx
        int bx = (int)((sqrtf(8.f * (float)tt + 1.f) - 1.f) * 0.5f);
        while ((bx + 1) * (bx + 2) / 2 <= tt) ++bx;
        while (bx * (bx + 1) / 2 > tt) --bx;
        int by = tt - bx * (bx + 1) / 2;
        const int bm = by * BM;   // bm <= bn
        const int bn = bx * BN;

        f32x4 acc[4][4];
        #pragma unroll
        for (int i = 0; i < 4; ++i)
            #pragma unroll
            for (int j = 0; j < 4; ++j) acc[i][j] = (f32x4){0.f, 0.f, 0.f, 0.f};

        #pragma unroll 1
        for (int win = 0; win < 4; ++win) {   // K = 64 per window
            __syncthreads();                  // prior reads / prior tile done
            const int wo = win * 64;
            #pragma unroll
            for (int j = 0; j < 4; ++j) {
                const unsigned short* ga =
                    Xp + (size_t)(bm + sg_r[j]) * D_K + wo + sg_u[j] * 8;
                const unsigned short* gb =
                    Xp + (size_t)(bn + sg_r[j]) * D_K + wo + sg_u[j] * 8;
                load_lds16(ga, al[j]);
                load_lds16(gb, bl[j]);
            }
            __syncthreads();                  // staging drained

            s16x8 a[4][2], b[4][2];
            #pragma unroll
            for (int mi = 0; mi < 4; ++mi) {
                int rb = (wrow + mi * 16 + fr) * 64;
                #pragma unroll
                for (int h = 0; h < 2; ++h) {
                    int s = (h * 4 + quad) ^ (fr & 7);
                    a[mi][h] = *reinterpret_cast<const s16x8*>(&Atile[rb + s * 8]);
                }
            }
            #pragma unroll
            for (int ni = 0; ni < 4; ++ni) {
                int rb = (wcol + ni * 16 + fr) * 64;
                #pragma unroll
                for (int h = 0; h < 2; ++h) {
                    int s = (h * 4 + quad) ^ (fr & 7);
                    b[ni][h] = *reinterpret_cast<const s16x8*>(&Btile[rb + s * 8]);
                }
            }
            #pragma unroll
            for (int mi = 0; mi < 4; ++mi)
                #pragma unroll
                for (int ni = 0; ni < 4; ++ni) {
                    acc[mi][ni] = __builtin_amdgcn_mfma_f32_16x16x32_bf16(
                        a[mi][0], b[ni][0], acc[mi][ni], 0, 0, 0);
                    acc[mi][ni] = __builtin_amdgcn_mfma_f32_16x16x32_bf16(
                        a[mi][1], b[ni][1], acc[mi][ni], 0, 0, 0);
                }
        }

        // -------- epilogue: dist + row mining + col mining -----------------
        int   ct[4]; float csq[4];
        #pragma unroll
        for (int ni = 0; ni < 4; ++ni) {
            int c = bn + wcol + ni * 16 + fr;
            ct[ni] = tgt[c]; csq[ni] = sq[c];
        }
        float cap[4], can[4];
        #pragma unroll
        for (int ni = 0; ni < 4; ++ni) { cap[ni] = -INF; can[ni] = INF; }

        #pragma unroll
        for (int mi = 0; mi < 4; ++mi) {
            #pragma unroll
            for (int reg = 0; reg < 4; ++reg) {
                int rl = wrow + mi * 16 + quad * 4 + reg;
                int rt = tgt[bm + rl]; float rsq = sq[bm + rl];
                float rap = -INF, ran = INF;
                #pragma unroll
                for (int ni = 0; ni < 4; ++ni) {
                    float d = rsq + csq[ni] - 2.f * acc[mi][ni][reg];
                    bool pos = (rt == ct[ni]);
                    if (pos) { rap = fmaxf(rap, d); cap[ni] = fmaxf(cap[ni], d); }
                    else     { ran = fminf(ran, d); can[ni] = fminf(can[ni], d); }
                }
                #pragma unroll
                for (int o = 1; o < 16; o <<= 1) {
                    rap = fmaxf(rap, __shfl_xor(rap, o, 64));
                    ran = fminf(ran, __shfl_xor(ran, o, 64));
                }
                if (fr == 0) {
                    atomicMax(&apk[bm + rl], fkey(rap));
                    atomicMin(&ank[bm + rl], fkey(ran));
                }
            }
        }
        #pragma unroll
        for (int ni = 0; ni < 4; ++ni) {
            #pragma unroll
            for (int o = 16; o < 64; o <<= 1) {
                cap[ni] = fmaxf(cap[ni], __shfl_xor(cap[ni], o, 64));
                can[ni] = fminf(can[ni], __shfl_xor(can[ni], o, 64));
            }
        }
        if (lane < 16) {
            #pragma unroll
            for (int ni = 0; ni < 4; ++ni) {
                int c = bn + wcol + ni * 16 + lane;
                atomicMax(&apk[c], fkey(cap[ni]));
                atomicMin(&ank[c], fkey(can[ni]));
            }
        }
    }
}

// ---- kernel 3: loss/prec partial sums + last-block finalize ---------------
__global__ __launch_bounds__(256) void final_kernel(const unsigned* __restrict__ apk,
        const unsigned* __restrict__ ank, float* __restrict__ acc2,
        float* __restrict__ out) {
    __shared__ float s_sum[4], s_cnt[4];
    int i = blockIdx.x * 256 + threadIdx.x;
    float ap = kval(apk[i]);
    float an = kval(ank[i]);
    float v  = ap - an + MARGIN;
    float sum = v > 0.f ? v : 0.f;
    float cnt = an > ap ? 1.f : 0.f;
    #pragma unroll
    for (int o = 32; o > 0; o >>= 1) {
        sum += __shfl_down(sum, o, 64);
        cnt += __shfl_down(cnt, o, 64);
    }
    int wave = threadIdx.x >> 6, lane = threadIdx.x & 63;
    if (lane == 0) { s_sum[wave] = sum; s_cnt[wave] = cnt; }
    __syncthreads();
    if (threadIdx.x == 0) {
        float ts = 0.f, tc = 0.f;
        #pragma unroll
        for (int w = 0; w < 4; ++w) { ts += s_sum[w]; tc += s_cnt[w]; }
        atomicAdd(&acc2[0], ts);
        atomicAdd(&acc2[1], tc);
        __threadfence();
        unsigned ticket = atomicAdd(reinterpret_cast<unsigned*>(acc2) + 2, 1u);
        if (ticket == gridDim.x - 1) {
            float fs = atomicAdd(&acc2[0], 0.f);
            float fc = atomicAdd(&acc2[1], 0.f);
            out[0] = fs / (float)B_N;
            out[1] = fc / (float)B_N;
        }
    }
}

extern "C" void kernel_launch(void* const* d_in, const int* in_sizes, int n_in,
                              void* d_out, int out_size, void* d_ws, size_t ws_size,
                              hipStream_t stream) {
    const float* X   = (const float*)d_in[0];
    const int*   tgt = (const int*)d_in[1];

    char* ws = (char*)d_ws;
    float*          sq   = (float*)ws;                    // 32 KB
    unsigned*       apk  = (unsigned*)(ws + 32768);       // 32 KB
    unsigned*       ank  = (unsigned*)(ws + 65536);       // 32 KB
    float*          acc2 = (float*)(ws + 98304);          // 12 B
    unsigned short* Xp   = (unsigned short*)(ws + 131072);// 4 MB

    float* out = (float*)d_out;

    prep_kernel<<<B_N / 4, 256, 0, stream>>>(X, sq, apk, ank, Xp, acc2);
    dist_kernel<<<(64 * 65) / 2 / NTILE, 256, 0, stream>>>(Xp, tgt, sq, apk, ank);
    final_kernel<<<B_N / 256, 256, 0, stream>>>(apk, ank, acc2, out);
}

// Round 8
// 117.022 us; speedup vs baseline: 1.4936x; 1.4936x over previous
//
#include <hip/hip_runtime.h>
#include <hip/hip_bf16.h>

#define B_N 8192
#define D_K 256
#define MARGIN 0.3f

typedef float f32x4 __attribute__((ext_vector_type(4)));
typedef short s16x8 __attribute__((ext_vector_type(8)));

// Order-preserving float->uint for atomicMax/atomicMin on floats.
__device__ __forceinline__ unsigned fkey(float f) {
    unsigned u = __float_as_uint(f);
    return (u & 0x80000000u) ? ~u : (u | 0x80000000u);
}
__device__ __forceinline__ float kval(unsigned k) {
    return (k & 0x80000000u) ? __uint_as_float(k ^ 0x80000000u)
                             : __uint_as_float(~k);
}

// async 16B global -> LDS (LDS dest = wave-uniform base + lane*16)
__device__ __forceinline__ void load_lds16(const unsigned short* g,
                                           unsigned short* l) {
    __builtin_amdgcn_global_load_lds(
        (const __attribute__((address_space(1))) unsigned int*)g,
        (__attribute__((address_space(3))) unsigned int*)l, 16, 0, 0);
}

// ---- kernel 1: bf16 round + norms OF ROUNDED VALUES + init ----------------
// Xp layout: [row][k] bf16, row stride 256 shorts (512 B).
// sq[row] = sum(hi^2) in fp32 -> dist is exactly ||xh_i - xh_j||^2 (stable).
__global__ __launch_bounds__(256) void prep_kernel(const float* __restrict__ X,
        float* __restrict__ sq, unsigned* __restrict__ apk,
        unsigned* __restrict__ ank, unsigned short* __restrict__ Xp,
        float* __restrict__ acc2) {
    int row  = (blockIdx.x << 2) + (threadIdx.x >> 6);
    int lane = threadIdx.x & 63;
    const float4 v = reinterpret_cast<const float4*>(X + (size_t)row * D_K)[lane];

    float xs[4] = {v.x, v.y, v.z, v.w};
    ushort4 hv;
    unsigned short* hp = &hv.x;
    float s = 0.f;
    #pragma unroll
    for (int i = 0; i < 4; ++i) {
        __hip_bfloat16 h = __float2bfloat16(xs[i]);
        hp[i] = *reinterpret_cast<unsigned short*>(&h);
        float hf = __bfloat162float(h);
        s = fmaf(hf, hf, s);
    }
    *reinterpret_cast<ushort4*>(Xp + (size_t)row * D_K + lane * 4) = hv;

    #pragma unroll
    for (int o = 32; o > 0; o >>= 1) s += __shfl_down(s, o, 64);
    if (lane == 0) {
        sq[row]  = s;
        apk[row] = 0u;           // <= fkey(-inf)
        ank[row] = 0xFFFFFFFFu;  // >= fkey(+inf)
    }
    if (blockIdx.x == 0 && threadIdx.x == 0) {
        acc2[0] = 0.f; acc2[1] = 0.f;
        reinterpret_cast<unsigned*>(acc2)[2] = 0u;   // ticket counter
    }
}

// ---- kernel 2: LDS-staged single-bf16 MFMA dist, 1 tile/block -------------
#define BM 128
#define BN 128
// LDS tile per operand: 128 rows x 64 shorts (one 64-k window; 8x16B units,
// unit u of row r stored at slot u^(r&7) -> 2 lanes/bank on ds_read_b128)

__global__ __launch_bounds__(256, 4) void dist_kernel(
        const unsigned short* __restrict__ Xp,
        const int* __restrict__ tgt, const float* __restrict__ sq,
        unsigned* __restrict__ apk, unsigned* __restrict__ ank) {
    __shared__ unsigned short Atile[128 * 64];   // 16 KB
    __shared__ unsigned short Btile[128 * 64];   // 16 KB

    const int t    = threadIdx.x;
    const int lane = t & 63;
    const int wave = t >> 6;
    const int wrow = (wave >> 1) * 64;
    const int wcol = (wave & 1) * 64;
    const int fr   = lane & 15;
    const int quad = lane >> 4;
    const float INF = __int_as_float(0x7f800000);

    // triangular decode: blockIdx.x -> (bx, by), by <= bx
    int tt = blockIdx.x;
    int bx = (int)((sqrtf(8.f * (float)tt + 1.f) - 1.f) * 0.5f);
    while ((bx + 1) * (bx + 2) / 2 <= tt) ++bx;
    while (bx * (bx + 1) / 2 > tt) --bx;
    int by = tt - bx * (bx + 1) / 2;
    const int bm = by * BM;   // bm <= bn
    const int bn = bx * BN;

    // staging geometry: thread's 4 units per operand
    const unsigned short* ag[4];
    const unsigned short* bg[4];
    unsigned short* al[4];
    unsigned short* bl[4];
    #pragma unroll
    for (int j = 0; j < 4; ++j) {
        int g = wave * 64 + j * 256 + lane;   // 0..1023
        int r = g >> 3, s0 = g & 7;
        int u = s0 ^ (r & 7);
        ag[j] = Xp + (size_t)(bm + r) * D_K + u * 8;
        bg[j] = Xp + (size_t)(bn + r) * D_K + u * 8;
        al[j] = Atile + g * 8;                // wave base + lane*16B
        bl[j] = Btile + g * 8;
    }

    f32x4 acc[4][4];
    #pragma unroll
    for (int i = 0; i < 4; ++i)
        #pragma unroll
        for (int j = 0; j < 4; ++j) acc[i][j] = (f32x4){0.f, 0.f, 0.f, 0.f};

    #pragma unroll 1
    for (int win = 0; win < 4; ++win) {   // K = 64 per window
        __syncthreads();                  // prior fragment reads complete
        const int wo = win * 64;
        #pragma unroll
        for (int j = 0; j < 4; ++j) {
            load_lds16(ag[j] + wo, al[j]);
            load_lds16(bg[j] + wo, bl[j]);
        }
        __syncthreads();                  // staging drained

        s16x8 a[4][2], b[4][2];
        #pragma unroll
        for (int mi = 0; mi < 4; ++mi) {
            int rb = (wrow + mi * 16 + fr) * 64;
            #pragma unroll
            for (int h = 0; h < 2; ++h) {
                int s = (h * 4 + quad) ^ (fr & 7);
                a[mi][h] = *reinterpret_cast<const s16x8*>(&Atile[rb + s * 8]);
            }
        }
        #pragma unroll
        for (int ni = 0; ni < 4; ++ni) {
            int rb = (wcol + ni * 16 + fr) * 64;
            #pragma unroll
            for (int h = 0; h < 2; ++h) {
                int s = (h * 4 + quad) ^ (fr & 7);
                b[ni][h] = *reinterpret_cast<const s16x8*>(&Btile[rb + s * 8]);
            }
        }
        #pragma unroll
        for (int mi = 0; mi < 4; ++mi)
            #pragma unroll
            for (int ni = 0; ni < 4; ++ni) {
                acc[mi][ni] = __builtin_amdgcn_mfma_f32_16x16x32_bf16(
                    a[mi][0], b[ni][0], acc[mi][ni], 0, 0, 0);
                acc[mi][ni] = __builtin_amdgcn_mfma_f32_16x16x32_bf16(
                    a[mi][1], b[ni][1], acc[mi][ni], 0, 0, 0);
            }
    }

    // -------- epilogue: dist + row mining + col mining ---------------------
    int   ct[4]; float csq[4];
    #pragma unroll
    for (int ni = 0; ni < 4; ++ni) {
        int c = bn + wcol + ni * 16 + fr;
        ct[ni] = tgt[c]; csq[ni] = sq[c];
    }
    float cap[4], can[4];
    #pragma unroll
    for (int ni = 0; ni < 4; ++ni) { cap[ni] = -INF; can[ni] = INF; }

    #pragma unroll
    for (int mi = 0; mi < 4; ++mi) {
        #pragma unroll
        for (int reg = 0; reg < 4; ++reg) {
            int rl = wrow + mi * 16 + quad * 4 + reg;
            int rt = tgt[bm + rl]; float rsq = sq[bm + rl];
            float rap = -INF, ran = INF;
            #pragma unroll
            for (int ni = 0; ni < 4; ++ni) {
                float d = rsq + csq[ni] - 2.f * acc[mi][ni][reg];
                bool pos = (rt == ct[ni]);
                if (pos) { rap = fmaxf(rap, d); cap[ni] = fmaxf(cap[ni], d); }
                else     { ran = fminf(ran, d); can[ni] = fminf(can[ni], d); }
            }
            #pragma unroll
            for (int o = 1; o < 16; o <<= 1) {
                rap = fmaxf(rap, __shfl_xor(rap, o, 64));
                ran = fminf(ran, __shfl_xor(ran, o, 64));
            }
            if (fr == 0) {
                atomicMax(&apk[bm + rl], fkey(rap));
                atomicMin(&ank[bm + rl], fkey(ran));
            }
        }
    }
    #pragma unroll
    for (int ni = 0; ni < 4; ++ni) {
        #pragma unroll
        for (int o = 16; o < 64; o <<= 1) {
            cap[ni] = fmaxf(cap[ni], __shfl_xor(cap[ni], o, 64));
            can[ni] = fminf(can[ni], __shfl_xor(can[ni], o, 64));
        }
    }
    if (lane < 16) {
        #pragma unroll
        for (int ni = 0; ni < 4; ++ni) {
            int c = bn + wcol + ni * 16 + lane;
            atomicMax(&apk[c], fkey(cap[ni]));
            atomicMin(&ank[c], fkey(can[ni]));
        }
    }
}

// ---- kernel 3: loss/prec partial sums + last-block finalize ---------------
__global__ __launch_bounds__(256) void final_kernel(const unsigned* __restrict__ apk,
        const unsigned* __restrict__ ank, float* __restrict__ acc2,
        float* __restrict__ out) {
    __shared__ float s_sum[4], s_cnt[4];
    int i = blockIdx.x * 256 + threadIdx.x;
    float ap = kval(apk[i]);
    float an = kval(ank[i]);
    float v  = ap - an + MARGIN;
    float sum = v > 0.f ? v : 0.f;
    float cnt = an > ap ? 1.f : 0.f;
    #pragma unroll
    for (int o = 32; o > 0; o >>= 1) {
        sum += __shfl_down(sum, o, 64);
        cnt += __shfl_down(cnt, o, 64);
    }
    int wave = threadIdx.x >> 6, lane = threadIdx.x & 63;
    if (lane == 0) { s_sum[wave] = sum; s_cnt[wave] = cnt; }
    __syncthreads();
    if (threadIdx.x == 0) {
        float ts = 0.f, tc = 0.f;
        #pragma unroll
        for (int w = 0; w < 4; ++w) { ts += s_sum[w]; tc += s_cnt[w]; }
        atomicAdd(&acc2[0], ts);
        atomicAdd(&acc2[1], tc);
        __threadfence();
        unsigned ticket = atomicAdd(reinterpret_cast<unsigned*>(acc2) + 2, 1u);
        if (ticket == gridDim.x - 1) {
            float fs = atomicAdd(&acc2[0], 0.f);
            float fc = atomicAdd(&acc2[1], 0.f);
            out[0] = fs / (float)B_N;
            out[1] = fc / (float)B_N;
        }
    }
}

extern "C" void kernel_launch(void* const* d_in, const int* in_sizes, int n_in,
                              void* d_out, int out_size, void* d_ws, size_t ws_size,
                              hipStream_t stream) {
    const float* X   = (const float*)d_in[0];
    const int*   tgt = (const int*)d_in[1];

    char* ws = (char*)d_ws;
    float*          sq   = (float*)ws;                    // 32 KB
    unsigned*       apk  = (unsigned*)(ws + 32768);       // 32 KB
    unsigned*       ank  = (unsigned*)(ws + 65536);       // 32 KB
    float*          acc2 = (float*)(ws + 98304);          // 12 B
    unsigned short* Xp   = (unsigned short*)(ws + 131072);// 4 MB

    float* out = (float*)d_out;

    prep_kernel<<<B_N / 4, 256, 0, stream>>>(X, sq, apk, ank, Xp, acc2);
    dist_kernel<<<(64 * 65) / 2, 256, 0, stream>>>(Xp, tgt, sq, apk, ank);
    final_kernel<<<B_N / 256, 256, 0, stream>>>(apk, ank, acc2, out);
}